// Round 1
// baseline (1915.188 us; speedup 1.0000x reference)
//
#include <hip/hip_runtime.h>
#include <math.h>

// ---------------------------------------------------------------------------
// 2-layer GCN forward — bucketed counting-split, ZERO global atomics.
// R8 key change: layer-1 gathers were L2-capacity-missing (16MB table vs 4MB
// per-XCD L2) -> bound by the ~36G lines/s L3/HBM random-transaction rate.
// Split layer-1 into THREE feature-sliced passes, each gathering 8B fp16 rows
// from a 4MB table that fits per-XCD L2. Edge stream uses nontemporal loads
// so it cannot evict the table. Batching deepened 4->8 edges; buckets split
// across 2 blocks for balance. Partial aggregates merge into agg[n][12] via
// coalesced global atomics; k_mlp applies W1/b1/relu/W2 -> h2s.
//   k_count    : per-block LDS histogram over 512-node buckets (nt stream)
//   scan       : exclusive scan (bucket-major) -> scatter bases
//   k_scatter  : LDS cursors; edge_g[pos] = pack{w:32|collow:9|row:19}
//   k_prep     : per-bucket degw -> dinv; xs0/1/2 = fp16(dinv*x) 8B-row slices
//   k_pass x3  : acc[512][5] LDS; acc_k += w*xs_p[r][k]; merge into agg
//   k_mlp      : h2s = dinv*( relu(dinv*agg @ W1 + b1) @ W2 )
//   k_pull2_b  : acc[512][3] LDS; out = log_softmax(dinv*(sum+self)+b2)
// Fallback to the R1 atomic-scatter path if ws too small / n too large.
// ---------------------------------------------------------------------------

typedef unsigned long long u64;
typedef unsigned int u32;
typedef _Float16 f16;
typedef __attribute__((ext_vector_type(4))) _Float16 f16x4;

#define BKT    512        // nodes per bucket (collow = 9 bits)
#define NBMAX  1024       // max buckets (=> n <= 2^19, matches row:19 packing)
#define NBLK   512        // partition blocks for count/scatter
#define PST    5          // pass acc stride (coprime with 32 banks)
#define AGS    12         // agg row stride in floats (3 slices x 4)
#define AST2   3          // acc stride layer2

// ---------------- count / scan / scatter ----------------

__global__ __launch_bounds__(256) void k_count(const int* __restrict__ col,
                                               u32* __restrict__ hist_g,
                                               int NB, int E, int CH) {
    __shared__ u32 cnt[NBMAX];
    for (int b = threadIdx.x; b < NB; b += 256) cnt[b] = 0;
    __syncthreads();
    int blk = blockIdx.x;
    int s = blk * CH, e = min(s + CH, E);
    for (int i = s + threadIdx.x; i < e; i += 256) {
        int c = __builtin_nontemporal_load(col + i);
        atomicAdd(&cnt[c >> 9], 1u);               // LDS atomic
    }
    __syncthreads();
    for (int b = threadIdx.x; b < NB; b += 256)
        hist_g[(size_t)blk * NB + b] = cnt[b];     // coalesced
}

// logical index e = bucket*NBLK + blk ; physical = blk*NB + bucket
__global__ __launch_bounds__(256) void k_scan_local32(const u32* __restrict__ hist_g,
                                                      u32* __restrict__ base_g,
                                                      u32* __restrict__ bsum,
                                                      int NB, int M) {
    __shared__ u32 s[256];
    int t = threadIdx.x;
    int e = blockIdx.x * 256 + t;
    u32 v = 0;
    if (e < M) {
        int b = e / NBLK, blk = e % NBLK;
        v = hist_g[(size_t)blk * NB + b];
    }
    s[t] = v;
    __syncthreads();
    for (int off = 1; off < 256; off <<= 1) {
        u32 u = (t >= off) ? s[t - off] : 0;
        __syncthreads();
        s[t] += u;
        __syncthreads();
    }
    if (e < M) base_g[e] = s[t] - v;               // exclusive
    if (t == 255) bsum[blockIdx.x] = s[255];
}

__global__ __launch_bounds__(256) void k_scan_sums32(u32* __restrict__ bsum, int nb) {
    __shared__ u32 s[256];
    __shared__ u32 carry;
    int t = threadIdx.x;
    if (t == 0) carry = 0;
    __syncthreads();
    int chunks = (nb + 255) / 256;
    for (int ch = 0; ch < chunks; ch++) {
        int i = ch * 256 + t;
        u32 v = (i < nb) ? bsum[i] : 0;
        s[t] = v;
        __syncthreads();
        for (int off = 1; off < 256; off <<= 1) {
            u32 u = (t >= off) ? s[t - off] : 0;
            __syncthreads();
            s[t] += u;
            __syncthreads();
        }
        u32 incl = s[t];
        u32 my_carry = carry;
        if (i < nb) bsum[i] = incl - v + my_carry;
        __syncthreads();
        if (t == 0) carry = my_carry + s[255];
        __syncthreads();
    }
}

__global__ __launch_bounds__(256) void k_scan_add32(u32* __restrict__ base_g,
                                                    const u32* __restrict__ bsum,
                                                    int M) {
    int e = blockIdx.x * 256 + threadIdx.x;
    if (e < M) base_g[e] += bsum[blockIdx.x];
}

__global__ __launch_bounds__(256) void k_scatter(const int* __restrict__ row,
                                                 const int* __restrict__ col,
                                                 const float* __restrict__ w,
                                                 const u32* __restrict__ base_g,
                                                 u64* __restrict__ edge_g,
                                                 int NB, int E, int CH) {
    __shared__ u32 cursor[NBMAX];
    int blk = blockIdx.x;
    for (int b = threadIdx.x; b < NB; b += 256)
        cursor[b] = base_g[(size_t)b * NBLK + blk];
    __syncthreads();
    int s = blk * CH, e = min(s + CH, E);
    for (int i = s + threadIdx.x; i < e; i += 256) {
        int c = __builtin_nontemporal_load(col + i);
        int r = __builtin_nontemporal_load(row + i);
        float wv = __builtin_nontemporal_load(w + i);
        int b = c >> 9;
        u32 pos = atomicAdd(&cursor[b], 1u);       // LDS atomic
        u64 rec = ((u64)__float_as_uint(wv) << 32)
                | ((u64)(u32)(c & 511) << 19) | (u64)(u32)r;
        edge_g[pos] = rec;                         // merges in L2 (write-back)
    }
}

// ---------------- prep: deg -> dinv, xs slices = fp16(dinv * x) ----------------

__global__ __launch_bounds__(256) void k_prep(const u64* __restrict__ edge_g,
                                              const u32* __restrict__ base_g,
                                              const float* __restrict__ x,
                                              float* __restrict__ dinv_g,
                                              f16* __restrict__ xs0,
                                              f16* __restrict__ xs1,
                                              f16* __restrict__ xs2,
                                              int NB, int n, int E) {
    __shared__ float degw[BKT];
    int b = blockIdx.x;
    for (int j = threadIdx.x; j < BKT; j += 256) degw[j] = 1.0f;  // self-loop
    __syncthreads();
    int s = (int)base_g[(size_t)b * NBLK];
    int e = (b + 1 < NB) ? (int)base_g[(size_t)(b + 1) * NBLK] : E;
    for (int i = s + threadIdx.x; i < e; i += 256) {
        u64 rec = __builtin_nontemporal_load(edge_g + i);
        int cl = (int)(((u32)rec >> 19) & 511u);
        float wv = __uint_as_float((u32)(rec >> 32));
        atomicAdd(&degw[cl], wv);                  // LDS f32 atomic
    }
    __syncthreads();
    int node0 = b << 9;
    int nn = min(BKT, n - node0);
    for (int j = threadIdx.x; j < nn; j += 256) {
        int node = node0 + j;
        float dv = rsqrtf(degw[j]);
        dinv_g[node] = dv;
        const float* xp = x + (size_t)node * 11;
        f16x4 a, bq, c;
#pragma unroll
        for (int k = 0; k < 4; k++) a[k]  = (f16)(dv * xp[k]);
#pragma unroll
        for (int k = 0; k < 4; k++) bq[k] = (f16)(dv * xp[4 + k]);
        c[0] = (f16)(dv * xp[8]);
        c[1] = (f16)(dv * xp[9]);
        c[2] = (f16)(dv * xp[10]);
        c[3] = (f16)0.f;
        *(f16x4*)(xs0 + ((size_t)node << 2)) = a;
        *(f16x4*)(xs1 + ((size_t)node << 2)) = bq;
        *(f16x4*)(xs2 + ((size_t)node << 2)) = c;
    }
}

// ---------------- layer-1 feature-sliced pass ----------------
// grid (NB, 2): blockIdx.y splits each bucket's edge range in half.
// xsp: 4MB fp16 table (fits per-XCD L2). aggp: agg + 4*slice.

__global__ __launch_bounds__(512) void k_pass(const u64* __restrict__ edge_g,
                                              const u32* __restrict__ base_g,
                                              const f16* __restrict__ xsp,
                                              float* __restrict__ aggp,
                                              int NB, int n, int E) {
    __shared__ float acc[BKT * PST];   // 10 KB
    int b = blockIdx.x, sp = blockIdx.y;
    int node0 = b << 9;
    int nn = min(BKT, n - node0);
    if (sp == 0) {     // init with self term xs_p[node]
        for (int t = threadIdx.x; t < nn * 4; t += 512) {
            int j = t >> 2, k = t & 3;
            acc[j * PST + k] = (float)xsp[((size_t)(node0 + j) << 2) + k];
        }
    } else {
        for (int t = threadIdx.x; t < nn * 4; t += 512) {
            int j = t >> 2, k = t & 3;
            acc[j * PST + k] = 0.f;
        }
    }
    __syncthreads();
    int s = (int)base_g[(size_t)b * NBLK];
    int e = (b + 1 < NB) ? (int)base_g[(size_t)(b + 1) * NBLK] : E;
    int h = (e - s) >> 1;
    int s0 = s + sp * h;
    int e0 = (sp == 0) ? (s + h) : e;
    int i = s0 + threadIdx.x;
    // batch of 8 edges: 8 nt-stream loads, then 8 gathers in flight
    for (; i + 3584 < e0; i += 4096) {
        u64 r[8];
        f16x4 g[8];
#pragma unroll
        for (int q = 0; q < 8; q++)
            r[q] = __builtin_nontemporal_load(edge_g + i + q * 512);
#pragma unroll
        for (int q = 0; q < 8; q++)
            g[q] = *(const f16x4*)(xsp + ((size_t)((u32)r[q] & 0x7FFFFu) << 2));
#pragma unroll
        for (int q = 0; q < 8; q++) {
            int cl = (int)(((u32)r[q] >> 19) & 511u);
            float wv = __uint_as_float((u32)(r[q] >> 32));
            float* a = acc + cl * PST;
            atomicAdd(a + 0, wv * (float)g[q][0]);
            atomicAdd(a + 1, wv * (float)g[q][1]);
            atomicAdd(a + 2, wv * (float)g[q][2]);
            atomicAdd(a + 3, wv * (float)g[q][3]);
        }
    }
    for (; i < e0; i += 512) {
        u64 rq = __builtin_nontemporal_load(edge_g + i);
        f16x4 gq = *(const f16x4*)(xsp + ((size_t)((u32)rq & 0x7FFFFu) << 2));
        int cl = (int)(((u32)rq >> 19) & 511u);
        float wv = __uint_as_float((u32)(rq >> 32));
        float* a = acc + cl * PST;
        atomicAdd(a + 0, wv * (float)gq[0]);
        atomicAdd(a + 1, wv * (float)gq[1]);
        atomicAdd(a + 2, wv * (float)gq[2]);
        atomicAdd(a + 3, wv * (float)gq[3]);
    }
    __syncthreads();
    // merge partial into agg (coalesced global f32 atomics, 2 writers/addr)
    for (int t = threadIdx.x; t < nn * 4; t += 512) {
        int j = t >> 2, k = t & 3;
        atomicAdd(&aggp[(size_t)(node0 + j) * AGS + k], acc[j * PST + k]);
    }
}

// ---------------- MLP epilogue: agg -> h2s ----------------

__global__ __launch_bounds__(256) void k_mlp(const float* __restrict__ agg,
                                             const float* __restrict__ dinv_g,
                                             const float* __restrict__ W1,
                                             const float* __restrict__ b1,
                                             const float* __restrict__ W2,
                                             float* __restrict__ h2s, int n) {
    __shared__ float sW1[176];
    __shared__ float sb1[16];
    __shared__ float sW2[32];
    for (int t = threadIdx.x; t < 176; t += 256) sW1[t] = W1[t];
    if (threadIdx.x < 16) sb1[threadIdx.x] = b1[threadIdx.x];
    if (threadIdx.x >= 64 && threadIdx.x < 96) sW2[threadIdx.x - 64] = W2[threadIdx.x - 64];
    __syncthreads();
    int node = blockIdx.x * 256 + threadIdx.x;
    if (node >= n) return;
    float dv = dinv_g[node];
    const float4* ap = (const float4*)(agg + (size_t)node * AGS);
    float4 v0 = ap[0], v1 = ap[1], v2 = ap[2];
    float v[11];
    v[0] = dv * v0.x; v[1] = dv * v0.y; v[2]  = dv * v0.z; v[3] = dv * v0.w;
    v[4] = dv * v1.x; v[5] = dv * v1.y; v[6]  = dv * v1.z; v[7] = dv * v1.w;
    v[8] = dv * v2.x; v[9] = dv * v2.y; v[10] = dv * v2.z;
    float o0 = 0.f, o1 = 0.f;
#pragma unroll
    for (int f = 0; f < 16; f++) {
        float hh = sb1[f];
#pragma unroll
        for (int k = 0; k < 11; k++) hh += v[k] * sW1[k * 16 + f];
        hh = fmaxf(hh, 0.f);
        o0 += hh * sW2[f * 2 + 0];
        o1 += hh * sW2[f * 2 + 1];
    }
    float2 ov; ov.x = dv * o0; ov.y = dv * o1;   // h2s = dinv * h2
    *(float2*)(h2s + ((size_t)node << 1)) = ov;
}

// ---------------- bucketed pull layer 2 ----------------

__global__ __launch_bounds__(512) void k_pull2_b(const u64* __restrict__ edge_g,
                                                 const u32* __restrict__ base_g,
                                                 const float* __restrict__ h2s,
                                                 const float* __restrict__ dinv_g,
                                                 const float* __restrict__ b2,
                                                 float* __restrict__ out,
                                                 int NB, int n, int E) {
    __shared__ float acc[BKT * AST2];   // 6 KB
    int b = blockIdx.x;
    int node0 = b << 9;
    int nn = min(BKT, n - node0);
    for (int t = threadIdx.x; t < nn * 2; t += 512) {
        int j = t >> 1, f = t & 1;
        acc[j * AST2 + f] = h2s[(size_t)node0 * 2 + t];   // init with self term
    }
    __syncthreads();
    int s = (int)base_g[(size_t)b * NBLK];
    int e = (b + 1 < NB) ? (int)base_g[(size_t)(b + 1) * NBLK] : E;
    int i = s + threadIdx.x;
    for (; i + 3584 < e; i += 4096) {
        u64 r[8];
        float2 g[8];
#pragma unroll
        for (int q = 0; q < 8; q++)
            r[q] = __builtin_nontemporal_load(edge_g + i + q * 512);
#pragma unroll
        for (int q = 0; q < 8; q++)
            g[q] = *(const float2*)(h2s + (size_t)((u32)r[q] & 0x7FFFFu) * 2);
#pragma unroll
        for (int q = 0; q < 8; q++) {
            int cl = (int)(((u32)r[q] >> 19) & 511u);
            float wv = __uint_as_float((u32)(r[q] >> 32));
            atomicAdd(&acc[cl * AST2 + 0], wv * g[q].x);
            atomicAdd(&acc[cl * AST2 + 1], wv * g[q].y);
        }
    }
    for (; i < e; i += 512) {
        u64 rq = __builtin_nontemporal_load(edge_g + i);
        float2 gq = *(const float2*)(h2s + (size_t)((u32)rq & 0x7FFFFu) * 2);
        int cl = (int)(((u32)rq >> 19) & 511u);
        float wv = __uint_as_float((u32)(rq >> 32));
        atomicAdd(&acc[cl * AST2 + 0], wv * gq.x);
        atomicAdd(&acc[cl * AST2 + 1], wv * gq.y);
    }
    __syncthreads();
    float c0 = b2[0], c1 = b2[1];
    for (int j = threadIdx.x; j < nn; j += 512) {
        int node = node0 + j;
        float dv = dinv_g[node];
        float v0 = dv * acc[j * AST2 + 0] + c0;
        float v1 = dv * acc[j * AST2 + 1] + c1;
        float m = fmaxf(v0, v1);
        float lse = m + logf(expf(v0 - m) + expf(v1 - m));
        float2 ov; ov.x = v0 - lse; ov.y = v1 - lse;
        *(float2*)(out + (size_t)node * 2) = ov;
    }
}

// ---------------- fallback atomic-scatter kernels (R1 proven path) ----------------

__global__ __launch_bounds__(256) void k_init_deg(float* deg, int n) {
    int i = blockIdx.x * blockDim.x + threadIdx.x;
    if (i < n) deg[i] = 1.0f;
}

__global__ __launch_bounds__(256) void k_deg_accum(const int* __restrict__ col,
                                                   const float* __restrict__ w,
                                                   float* __restrict__ deg, int E) {
    int i = blockIdx.x * blockDim.x + threadIdx.x;
    if (i < E) atomicAdd(&deg[col[i]], w[i]);
}

__global__ __launch_bounds__(256) void k_rsqrt(float* deg, int n) {
    int i = blockIdx.x * blockDim.x + threadIdx.x;
    if (i < n) {
        float d = deg[i];
        deg[i] = (d > 0.0f) ? rsqrtf(d) : 0.0f;
    }
}

__global__ __launch_bounds__(256) void k_gemm1_plain(const float* __restrict__ x,
                                                     const float* __restrict__ W1,
                                                     float* __restrict__ h1, int n) {
    __shared__ float sW[176];
    for (int t = threadIdx.x; t < 176; t += blockDim.x) sW[t] = W1[t];
    __syncthreads();
    int i = blockIdx.x * blockDim.x + threadIdx.x;
    if (i >= n) return;
    float xi[11];
#pragma unroll
    for (int k = 0; k < 11; k++) xi[k] = x[(size_t)i * 11 + k];
#pragma unroll
    for (int f = 0; f < 16; f++) {
        float acc = 0.0f;
#pragma unroll
        for (int k = 0; k < 11; k++) acc += xi[k] * sW[k * 16 + f];
        h1[(size_t)i * 16 + f] = acc;
    }
}

__global__ __launch_bounds__(256) void k_scatter16(const int* __restrict__ row,
                                                   const int* __restrict__ col,
                                                   const float* __restrict__ w,
                                                   const float* __restrict__ dinv,
                                                   const float* __restrict__ h1,
                                                   float* __restrict__ acc, int E) {
    int i = blockIdx.x * blockDim.x + threadIdx.x;
    if (i >= E) return;
    int r = row[i], c = col[i];
    float nw = dinv[r] * w[i] * dinv[c];
    const float4* hr = (const float4*)(h1 + (size_t)r * 16);
    float* o = acc + (size_t)c * 16;
#pragma unroll
    for (int q = 0; q < 4; q++) {
        float4 hv = hr[q];
        atomicAdd(o + q * 4 + 0, nw * hv.x);
        atomicAdd(o + q * 4 + 1, nw * hv.y);
        atomicAdd(o + q * 4 + 2, nw * hv.z);
        atomicAdd(o + q * 4 + 3, nw * hv.w);
    }
}

__global__ __launch_bounds__(256) void k_post1(const float* __restrict__ h1,
                                               const float* __restrict__ dinv,
                                               const float* __restrict__ b1,
                                               float* __restrict__ acc, int n) {
    int i = blockIdx.x * blockDim.x + threadIdx.x;
    if (i >= n) return;
    float dv = dinv[i];
    float cs = dv * dv;
#pragma unroll
    for (int f = 0; f < 16; f++) {
        float v = acc[(size_t)i * 16 + f] + cs * h1[(size_t)i * 16 + f] + b1[f];
        acc[(size_t)i * 16 + f] = v > 0.0f ? v : 0.0f;
    }
}

__global__ __launch_bounds__(256) void k_gemm2(const float* __restrict__ hrelu,
                                               const float* __restrict__ W2,
                                               float* __restrict__ h2, int n) {
    __shared__ float sW[32];
    for (int t = threadIdx.x; t < 32; t += blockDim.x) sW[t] = W2[t];
    __syncthreads();
    int i = blockIdx.x * blockDim.x + threadIdx.x;
    if (i >= n) return;
    float a0 = 0.0f, a1 = 0.0f;
#pragma unroll
    for (int f = 0; f < 16; f++) {
        float h = hrelu[(size_t)i * 16 + f];
        a0 += h * sW[f * 2 + 0];
        a1 += h * sW[f * 2 + 1];
    }
    h2[(size_t)i * 2 + 0] = a0;
    h2[(size_t)i * 2 + 1] = a1;
}

__global__ __launch_bounds__(256) void k_scatter2(const int* __restrict__ row,
                                                  const int* __restrict__ col,
                                                  const float* __restrict__ w,
                                                  const float* __restrict__ dinv,
                                                  const float* __restrict__ h2,
                                                  float* __restrict__ out, int E) {
    int i = blockIdx.x * blockDim.x + threadIdx.x;
    if (i >= E) return;
    int r = row[i], c = col[i];
    float nw = dinv[r] * w[i] * dinv[c];
    atomicAdd(&out[(size_t)c * 2 + 0], nw * h2[(size_t)r * 2 + 0]);
    atomicAdd(&out[(size_t)c * 2 + 1], nw * h2[(size_t)r * 2 + 1]);
}

__global__ __launch_bounds__(256) void k_final(const float* __restrict__ h2,
                                               const float* __restrict__ dinv,
                                               const float* __restrict__ b2,
                                               float* __restrict__ out, int n) {
    int i = blockIdx.x * blockDim.x + threadIdx.x;
    if (i >= n) return;
    float dv = dinv[i];
    float cs = dv * dv;
    float v0 = out[(size_t)i * 2 + 0] + cs * h2[(size_t)i * 2 + 0] + b2[0];
    float v1 = out[(size_t)i * 2 + 1] + cs * h2[(size_t)i * 2 + 1] + b2[1];
    float m = fmaxf(v0, v1);
    float lse = m + logf(expf(v0 - m) + expf(v1 - m));
    out[(size_t)i * 2 + 0] = v0 - lse;
    out[(size_t)i * 2 + 1] = v1 - lse;
}

// ---------------- launch ----------------

static inline size_t align64(size_t x) { return (x + 63) & ~(size_t)63; }

extern "C" void kernel_launch(void* const* d_in, const int* in_sizes, int n_in,
                              void* d_out, int out_size, void* d_ws, size_t ws_size,
                              hipStream_t stream) {
    const float* x  = (const float*)d_in[0];
    const int*   ei = (const int*)d_in[1];
    const float* ew = (const float*)d_in[2];
    const float* W1 = (const float*)d_in[3];
    const float* b1 = (const float*)d_in[4];
    const float* W2 = (const float*)d_in[5];
    const float* b2 = (const float*)d_in[6];

    const int n = in_sizes[0] / 11;
    const int E = in_sizes[2];
    const int* rowp = ei;       // sources
    const int* colp = ei + E;   // targets

    const int TB = 256;
    const int gN = (n + TB - 1) / TB;
    const int gE = (E + TB - 1) / TB;

    const int NB = (n + BKT - 1) / BKT;            // buckets
    const int CH = (E + NBLK - 1) / NBLK;          // edges per partition block
    const int M  = NB * NBLK;                      // scan length
    const int SB = (M + 255) / 256;                // scan blocks

    // --- workspace layout (bucketed path) ---
    char* base = (char*)d_ws;
    size_t o_hist = 0;                                        // u32 M
    size_t o_base = align64(o_hist + (size_t)M * 4);          // u32 M
    size_t o_bsum = align64(o_base + (size_t)M * 4);          // u32 SB
    size_t o_dinv = align64(o_bsum + (size_t)SB * 4);         // f32 n
    size_t o_xs0  = align64(o_dinv + (size_t)n * 4);          // f16 4n (8B rows)
    size_t o_xs1  = align64(o_xs0 + (size_t)n * 8);           // f16 4n
    size_t o_xs2  = align64(o_xs1 + (size_t)n * 8);           // f16 4n
    size_t o_agg  = align64(o_xs2 + (size_t)n * 8);           // f32 12n
    size_t o_h2   = align64(o_agg + (size_t)n * AGS * 4);     // f32 2n
    size_t o_edge = align64(o_h2 + (size_t)n * 2 * 4);        // u64 E
    size_t needed = align64(o_edge + (size_t)E * 8);

    float* outf = (float*)d_out;

    if (ws_size >= needed && n <= (1 << 19) && NB <= NBMAX) {
        u32*   hist_g = (u32*)(base + o_hist);
        u32*   base_g = (u32*)(base + o_base);
        u32*   bsum   = (u32*)(base + o_bsum);
        float* dinv_g = (float*)(base + o_dinv);
        f16*   xs0    = (f16*)(base + o_xs0);
        f16*   xs1    = (f16*)(base + o_xs1);
        f16*   xs2    = (f16*)(base + o_xs2);
        float* agg    = (float*)(base + o_agg);
        float* h2s    = (float*)(base + o_h2);
        u64*   edge_g = (u64*)(base + o_edge);

        hipMemsetAsync(agg, 0, (size_t)n * AGS * sizeof(float), stream);
        k_count<<<NBLK, TB, 0, stream>>>(colp, hist_g, NB, E, CH);
        k_scan_local32<<<SB, TB, 0, stream>>>(hist_g, base_g, bsum, NB, M);
        k_scan_sums32<<<1, TB, 0, stream>>>(bsum, SB);
        k_scan_add32<<<SB, TB, 0, stream>>>(base_g, bsum, M);
        k_scatter<<<NBLK, TB, 0, stream>>>(rowp, colp, ew, base_g, edge_g, NB, E, CH);
        k_prep<<<NB, TB, 0, stream>>>(edge_g, base_g, x, dinv_g, xs0, xs1, xs2, NB, n, E);
        dim3 gp(NB, 2, 1);
        k_pass<<<gp, 512, 0, stream>>>(edge_g, base_g, xs0, agg + 0, NB, n, E);
        k_pass<<<gp, 512, 0, stream>>>(edge_g, base_g, xs1, agg + 4, NB, n, E);
        k_pass<<<gp, 512, 0, stream>>>(edge_g, base_g, xs2, agg + 8, NB, n, E);
        k_mlp<<<gN, TB, 0, stream>>>(agg, dinv_g, W1, b1, W2, h2s, n);
        k_pull2_b<<<NB, 512, 0, stream>>>(edge_g, base_g, h2s, dinv_g, b2, outf, NB, n, E);
    } else {
        // fallback: atomic-scatter path (R1)
        float* ws   = (float*)d_ws;
        float* dinv = ws;
        float* h1   = ws + (size_t)n;
        float* acc1 = ws + (size_t)n * 17;

        k_init_deg<<<gN, TB, 0, stream>>>(dinv, n);
        k_deg_accum<<<gE, TB, 0, stream>>>(colp, ew, dinv, E);
        k_rsqrt<<<gN, TB, 0, stream>>>(dinv, n);

        k_gemm1_plain<<<gN, TB, 0, stream>>>(x, W1, h1, n);
        hipMemsetAsync(acc1, 0, (size_t)n * 16 * sizeof(float), stream);
        k_scatter16<<<gE, TB, 0, stream>>>(rowp, colp, ew, dinv, h1, acc1, E);
        k_post1<<<gN, TB, 0, stream>>>(h1, dinv, b1, acc1, n);

        float* h2 = h1;
        k_gemm2<<<gN, TB, 0, stream>>>(acc1, W2, h2, n);
        hipMemsetAsync(outf, 0, (size_t)n * 2 * sizeof(float), stream);
        k_scatter2<<<gE, TB, 0, stream>>>(rowp, colp, ew, dinv, h2, outf, E);
        k_final<<<gN, TB, 0, stream>>>(h2, dinv, b2, outf, n);
    }
}